// Round 3
// baseline (1458.157 us; speedup 1.0000x reference)
//
#include <hip/hip_runtime.h>
#include <math.h>

#define NN 50000
#define NE 512000
#define NE2 256000
#define SCALE 0.17677669529663687f   // 1/sqrt(32)
#define EPSV 1e-5f

// ---- workspace layout (float offsets), total ~404 MB of ~1 GiB ----
#define OFF_QKV     0UL           // 50000*384 bf16
#define OFF_CC      9600000UL     // 512000*256 bf16  [ea2 | ea3]
#define OFF_EX1     75136000UL    // 512000*4 f32
#define OFF_EX2     77184000UL
#define OFF_AGG     79232000UL    // 50000*128 f32 (written, no init)
#define OFF_XH      85632000UL    // 256000*32 f32
#define OFF_ATTR    93824000UL    // 50000*32
#define OFF_O1      95424000UL
#define OFF_XGAT    97024000UL
#define OFF_WQKVT   98624000UL    // 384*128 bf16
#define OFF_WE23T   98648576UL    // 256*128 bf16
#define OFF_BQKV    98664960UL    // 384 f32
#define OFF_BE23    98665344UL    // 256 f32
#define OFF_ROWPTR  98665600UL    // 50001 int
#define OFF_CURSOR  98715604UL    // 50000 int
#define OFF_ELIST   98765604UL    // 512000 int
// ---- zero region ----
#define OFF_DCNT    99277604UL    // 50000 int
#define OFF_O1ACC   99327604UL    // 50000*32 f32
#define OFF_DEGB    100927604UL   // 50000 f32
#define OFF_STATS   100977604UL   // 64 f32
#define ZERO_START  OFF_DCNT
#define ZERO_END    100977668UL

typedef __attribute__((ext_vector_type(8))) short bf16x8;
typedef __attribute__((ext_vector_type(8))) unsigned short us8;
typedef __attribute__((ext_vector_type(4))) float f32x4;

__device__ __forceinline__ unsigned short f2bf(float f) {
    unsigned int u = __float_as_uint(f);
    unsigned int r = (u + 0x7FFFu + ((u >> 16) & 1u)) >> 16;
    return (unsigned short)r;
}
__device__ __forceinline__ float bf2f(unsigned short u) {
    return __uint_as_float(((unsigned int)u) << 16);
}

// ---------------- pack: Bt[j][k] = W[k][j] (bf16), W is 128 x 128 ----------------
__global__ void pack_wt(const float* __restrict__ W, unsigned short* __restrict__ Bt) {
    const int idx = blockIdx.x * 256 + threadIdx.x;   // 16384
    const int j = idx >> 7;
    const int k = idx & 127;
    Bt[idx] = f2bf(W[k * 128 + j]);
}

// ---------------- pack biases ----------------
__global__ void bias_pack(const float* __restrict__ bq, const float* __restrict__ bk,
                          const float* __restrict__ bv, const float* __restrict__ be2,
                          const float* __restrict__ be3, float* __restrict__ BQKV,
                          float* __restrict__ BE23) {
    const int idx = blockIdx.x * 256 + threadIdx.x;
    if (idx < 384) {
        BQKV[idx] = (idx < 128) ? bq[idx] : (idx < 256 ? bk[idx - 128] : bv[idx - 256]);
    } else if (idx < 640) {
        const int j = idx - 384;
        BE23[j] = (j < 128) ? be2[j] : be3[j - 128];
    }
}

// ---------------- generic MFMA GEMM: out = bf16(A(Mx128 f32) @ Bt^T + bias) ----------------
// Bt is (Ntot x 128) bf16 (row j = output column j). Tile 128M x 128N slab-looped.
__global__ __launch_bounds__(256)
void gemm_node(const float* __restrict__ A, const unsigned short* __restrict__ Bt,
               const float* __restrict__ bias, unsigned short* __restrict__ out,
               int M, int Ntot) {
    __shared__ unsigned short As[2][128 * 72];
    __shared__ unsigned short Bs[2][128 * 72];
    const int tid = threadIdx.x;
    const int wave = tid >> 6;
    const int lane = tid & 63;
    const int quad = lane >> 4;
    const int l16 = lane & 15;
    const int m0 = (wave & 1) * 64;
    const int n0 = (wave >> 1) * 64;
    const size_t r0 = (size_t)blockIdx.x * 128;

    // stage A (both K-halves), fp32 -> bf16
    #pragma unroll
    for (int kh = 0; kh < 2; kh++) {
        #pragma unroll
        for (int i = 0; i < 8; i++) {
            const int q = tid + 256 * i;
            const int row = q >> 4;
            const int c4 = q & 15;
            const long gr = (long)r0 + row;
            float4 a4 = {0.f, 0.f, 0.f, 0.f};
            if (gr < M) a4 = *(const float4*)(A + gr * 128 + kh * 64 + c4 * 4);
            ushort4 b4;
            b4.x = f2bf(a4.x); b4.y = f2bf(a4.y); b4.z = f2bf(a4.z); b4.w = f2bf(a4.w);
            *(ushort4*)(&As[kh][row * 72 + c4 * 4]) = b4;
        }
    }
    const int nslab = Ntot >> 7;
    for (int s = 0; s < nslab; s++) {
        __syncthreads();   // prev slab frag reads done (and A-visibility on s=0 via next sync)
        #pragma unroll
        for (int kh = 0; kh < 2; kh++) {
            const int n = tid >> 1;
            const int koff = (tid & 1) * 32;
            const unsigned short* src = Bt + (size_t)(s * 128 + n) * 128 + kh * 64 + koff;
            #pragma unroll
            for (int u = 0; u < 4; u++)
                *(us8*)(&Bs[kh][n * 72 + koff + 8 * u]) = *(const us8*)(src + 8 * u);
        }
        __syncthreads();
        f32x4 acc[4][4];
        #pragma unroll
        for (int i = 0; i < 4; i++)
            #pragma unroll
            for (int j = 0; j < 4; j++) acc[i][j] = (f32x4){0.f, 0.f, 0.f, 0.f};
        #pragma unroll
        for (int kh = 0; kh < 2; kh++) {
            #pragma unroll
            for (int kc = 0; kc < 64; kc += 32) {
                bf16x8 af[4], bfr[4];
                #pragma unroll
                for (int i = 0; i < 4; i++)
                    af[i] = *(const bf16x8*)(&As[kh][(m0 + 16 * i + l16) * 72 + kc + quad * 8]);
                #pragma unroll
                for (int j = 0; j < 4; j++)
                    bfr[j] = *(const bf16x8*)(&Bs[kh][(n0 + 16 * j + l16) * 72 + kc + quad * 8]);
                #pragma unroll
                for (int i = 0; i < 4; i++)
                    #pragma unroll
                    for (int j = 0; j < 4; j++)
                        acc[i][j] = __builtin_amdgcn_mfma_f32_16x16x32_bf16(af[i], bfr[j], acc[i][j], 0, 0, 0);
            }
        }
        // epilogue
        #pragma unroll
        for (int j = 0; j < 4; j++) {
            const int col = n0 + 16 * j + l16;
            const float bcol = bias[s * 128 + col];
            #pragma unroll
            for (int i = 0; i < 4; i++) {
                #pragma unroll
                for (int r = 0; r < 4; r++) {
                    const long row = (long)r0 + m0 + 16 * i + quad * 4 + r;
                    if (row < M)
                        out[row * Ntot + s * 128 + col] = f2bf(acc[i][j][r] + bcol);
                }
            }
        }
    }
}

// ---------------- pass1: per-edge exp-logits (no atomics) ----------------
__global__ void pass1(const int* __restrict__ eidx, const unsigned short* __restrict__ qkv,
                      const unsigned short* __restrict__ Cc,
                      float* __restrict__ ex1, float* __restrict__ ex2) {
    const size_t e = (size_t)blockIdx.x * 4 + (threadIdx.x >> 6);
    const int lane = threadIdx.x & 63;
    const int src = eidx[e];
    const int dst = eidx[NE + e];
    const unsigned int qp = *(const unsigned int*)(qkv + (size_t)dst * 384 + 2 * lane);
    const unsigned int kp = *(const unsigned int*)(qkv + (size_t)src * 384 + 128 + 2 * lane);
    const unsigned int ep = *(const unsigned int*)(Cc + (size_t)e * 256 + 2 * lane);
    const float qx = bf2f((unsigned short)(qp & 0xFFFF)), qy = bf2f((unsigned short)(qp >> 16));
    const float kx = bf2f((unsigned short)(kp & 0xFFFF)), ky = bf2f((unsigned short)(kp >> 16));
    const float e2x = bf2f((unsigned short)(ep & 0xFFFF)), e2y = bf2f((unsigned short)(ep >> 16));
    float p1 = qx * kx + qy * ky;
    float p2 = qx * e2x + qy * e2y;
    #pragma unroll
    for (int off = 8; off > 0; off >>= 1) {
        p1 += __shfl_down(p1, off, 16);
        p2 += __shfl_down(p2, off, 16);
    }
    if ((lane & 15) == 0) {
        const int h = lane >> 4;
        ex1[e * 4 + h] = __expf(p1 * SCALE);
        ex2[e * 4 + h] = __expf(p2 * SCALE);
    }
}

// ---------------- CSR build ----------------
__global__ void csr_hist(const int* __restrict__ eidx, int* __restrict__ dcnt) {
    const int e = blockIdx.x * 256 + threadIdx.x;
    atomicAdd(&dcnt[eidx[NE + e]], 1);
}

__global__ __launch_bounds__(1024)
void scan50k(const int* __restrict__ dcnt, int* __restrict__ rowptr, int* __restrict__ cursor) {
    __shared__ int part[1024];
    const int t = threadIdx.x;
    const int per = 49;
    const int base = t * per;
    int s = 0;
    for (int i = 0; i < per; i++) {
        const int n = base + i;
        if (n < NN) s += dcnt[n];
    }
    part[t] = s;
    __syncthreads();
    for (int off = 1; off < 1024; off <<= 1) {
        const int vv = (t >= off) ? part[t - off] : 0;
        __syncthreads();
        part[t] += vv;
        __syncthreads();
    }
    int run = (t == 0) ? 0 : part[t - 1];
    for (int i = 0; i < per; i++) {
        const int n = base + i;
        if (n < NN) {
            rowptr[n] = run;
            cursor[n] = run;
            run += dcnt[n];
        }
    }
    if (base <= NN - 1 && NN - 1 < base + per) rowptr[NN] = run;
}

__global__ void csr_scatter(const int* __restrict__ eidx, int* __restrict__ cursor,
                            int* __restrict__ elist) {
    const int e = blockIdx.x * 256 + threadIdx.x;
    const int dst = eidx[NE + e];
    const int pos = atomicAdd(&cursor[dst], 1);
    elist[pos] = e;
}

// ---------------- pass2: per-node gather (no atomics) ----------------
__global__ void pass2_gather(const int* __restrict__ eidx, const int* __restrict__ rowptr,
                             const int* __restrict__ elist,
                             const unsigned short* __restrict__ qkv,
                             const unsigned short* __restrict__ Cc,
                             const float* __restrict__ ex1, const float* __restrict__ ex2,
                             float* __restrict__ agg) {
    const int n = blockIdx.x * 4 + (threadIdx.x >> 6);
    const int lane = threadIdx.x & 63;
    const int h = lane >> 4;
    const int beg = rowptr[n], end = rowptr[n + 1];
    float s1 = 0.f, s2 = 0.f;
    for (int i = beg; i < end; i++) {
        const int e = elist[i];
        s1 += ex1[(size_t)e * 4 + h];
        s2 += ex2[(size_t)e * 4 + h];
    }
    const float r1 = 1.f / (s1 + 1e-16f);
    const float r2 = 1.f / (s2 + 1e-16f);
    float ax = 0.f, ay = 0.f;
    for (int i = beg; i < end; i++) {
        const int e = elist[i];
        const int src = eidx[e];
        const float w1 = ex1[(size_t)e * 4 + h] * r1;
        const float w2 = ex2[(size_t)e * 4 + h] * r2;
        const unsigned int vp = *(const unsigned int*)(qkv + (size_t)src * 384 + 256 + 2 * lane);
        const unsigned int e3 = *(const unsigned int*)(Cc + (size_t)e * 256 + 128 + 2 * lane);
        ax += w1 * bf2f((unsigned short)(vp & 0xFFFF)) + w2 * bf2f((unsigned short)(e3 & 0xFFFF));
        ay += w1 * bf2f((unsigned short)(vp >> 16)) + w2 * bf2f((unsigned short)(e3 >> 16));
    }
    *(float2*)(agg + (size_t)n * 128 + 2 * lane) = make_float2(ax, ay);
}

// ---------------- generic (M x 128) @ (128 x 32) fp32 ----------------
__global__ void gemm_d128_o32(const float* __restrict__ A, const float* __restrict__ W,
                              float* __restrict__ out) {
    __shared__ float as[8 * 128];
    const int tid = threadIdx.x;
    const int p = tid & 31;
    const int mm = tid >> 5;
    const size_t m0 = (size_t)blockIdx.x * 8;
    ((float4*)as)[tid] = ((const float4*)(A + m0 * 128))[tid];
    __syncthreads();
    float c0 = 0.f, c1 = 0.f, c2 = 0.f, c3 = 0.f;
    const float4* as4 = (const float4*)as;
    #pragma unroll 8
    for (int i = 0; i < 32; i++) {
        const float4 a4 = as4[mm*32 + i];
        c0 += a4.x * W[(4*i+0)*32 + p];
        c1 += a4.y * W[(4*i+1)*32 + p];
        c2 += a4.z * W[(4*i+2)*32 + p];
        c3 += a4.w * W[(4*i+3)*32 + p];
    }
    out[(m0 + mm)*32 + p] = (c0 + c1) + (c2 + c3);
}

// ---------------- BN stats ----------------
__global__ void bn_stats(const float* __restrict__ xg, float* __restrict__ stats) {
    __shared__ float ls[256], lss[256];
    const int tid = threadIdx.x;
    float s = 0.f, ss = 0.f;
    for (size_t i = (size_t)blockIdx.x*256 + tid; i < (size_t)NN*32; i += (size_t)gridDim.x*256) {
        const float val = xg[i];
        s += val; ss += val * val;
    }
    ls[tid] = s; lss[tid] = ss;
    __syncthreads();
    if (tid < 32) {
        float as_ = 0.f, ass = 0.f;
        #pragma unroll
        for (int w = 0; w < 8; w++) { as_ += ls[tid + 32*w]; ass += lss[tid + 32*w]; }
        atomicAdd(&stats[tid], as_);
        atomicAdd(&stats[32 + tid], ass);
    }
}

// ---------------- BN apply + exact GELU ----------------
__global__ void bn_gelu(const float* __restrict__ xg, const float* __restrict__ stats,
                        const float* __restrict__ bnw, const float* __restrict__ bnb,
                        float* __restrict__ out) {
    const size_t i = (size_t)blockIdx.x * 256 + threadIdx.x;
    const int c = i & 31;
    const float mu = stats[c] * (1.0f / NN);
    const float var = stats[32 + c] * (1.0f / NN) - mu * mu;
    const float xn = bnw[c] * (xg[i] - mu) * rsqrtf(var + EPSV) + bnb[c];
    out[i] = 0.5f * xn * (1.0f + erff(xn * 0.70710678118654752f));
}

// ---------------- hypergraph scatter ----------------
__global__ void hyper_scatter(const float* __restrict__ xh, const int* __restrict__ eidx,
                              float* __restrict__ o1acc, float* __restrict__ degb) {
    const int tid = threadIdx.x;
    const int c = tid & 31;
    const size_t i = (size_t)blockIdx.x * 8 + (tid >> 5);
    const int src = eidx[i];
    const int dst = eidx[NE + i];
    const float xv = xh[i*32 + c];
    atomicAdd(&o1acc[(size_t)src*32 + c], xv);
    atomicAdd(&o1acc[(size_t)dst*32 + c], xv);
    if (c == 0) {
        atomicAdd(&degb[src], 1.0f);
        atomicAdd(&degb[dst], 1.0f);
    }
}

__global__ void o1_finalize(const float* __restrict__ o1acc, const float* __restrict__ degb,
                            const float* __restrict__ attr, float* __restrict__ o1) {
    const size_t i = (size_t)blockIdx.x * 256 + threadIdx.x;
    const int n = (int)(i >> 5);
    const float d = degb[n];
    const float binv = d > 0.f ? 1.0f / d : 0.0f;
    o1[i] = o1acc[i] * binv + attr[i];
}

__global__ void edge_out(const float* __restrict__ o1, const int* __restrict__ eidx,
                         const float* __restrict__ bh, float* __restrict__ out2) {
    const size_t idx = (size_t)blockIdx.x * 256 + threadIdx.x;
    const size_t i = idx >> 5;
    const int c = (int)(idx & 31);
    const int src = eidx[i];
    const int dst = eidx[NE + i];
    out2[idx] = 0.5f * (o1[(size_t)src*32 + c] + o1[(size_t)dst*32 + c]) + bh[c];
}

extern "C" void kernel_launch(void* const* d_in, const int* in_sizes, int n_in,
                              void* d_out, int out_size, void* d_ws, size_t ws_size,
                              hipStream_t stream) {
    const float* x    = (const float*)d_in[0];
    const float* eatt = (const float*)d_in[1];
    const float* Wq   = (const float*)d_in[2];
    const float* bq   = (const float*)d_in[3];
    const float* Wk   = (const float*)d_in[4];
    const float* bk   = (const float*)d_in[5];
    const float* Wv   = (const float*)d_in[6];
    const float* bv   = (const float*)d_in[7];
    const float* We2  = (const float*)d_in[8];
    const float* be2  = (const float*)d_in[9];
    const float* We3  = (const float*)d_in[10];
    const float* be3  = (const float*)d_in[11];
    const float* Wcon = (const float*)d_in[12];
    const float* bnw  = (const float*)d_in[13];
    const float* bnb  = (const float*)d_in[14];
    const float* Wh1  = (const float*)d_in[15];
    const float* Wh2  = (const float*)d_in[16];
    const float* bh   = (const float*)d_in[17];
    const int*   eidx = (const int*)d_in[18];

    float* ws = (float*)d_ws;
    unsigned short* qkv   = (unsigned short*)(ws + OFF_QKV);
    unsigned short* Cc    = (unsigned short*)(ws + OFF_CC);
    float* ex1   = ws + OFF_EX1;
    float* ex2   = ws + OFF_EX2;
    float* agg   = ws + OFF_AGG;
    float* xh    = ws + OFF_XH;
    float* attr  = ws + OFF_ATTR;
    float* o1    = ws + OFF_O1;
    float* xgat  = ws + OFF_XGAT;
    unsigned short* WQKVT = (unsigned short*)(ws + OFF_WQKVT);
    unsigned short* WE23T = (unsigned short*)(ws + OFF_WE23T);
    float* BQKV  = ws + OFF_BQKV;
    float* BE23  = ws + OFF_BE23;
    int* rowptr  = (int*)(ws + OFF_ROWPTR);
    int* cursor  = (int*)(ws + OFF_CURSOR);
    int* elist   = (int*)(ws + OFF_ELIST);
    int* dcnt    = (int*)(ws + OFF_DCNT);
    float* o1acc = ws + OFF_O1ACC;
    float* degb  = ws + OFF_DEGB;
    float* stats = ws + OFF_STATS;
    float* out0  = (float*)d_out;
    float* out1  = (float*)d_out + (size_t)NN * 32;

    hipMemsetAsync(ws + ZERO_START, 0, (ZERO_END - ZERO_START) * sizeof(float), stream);

    pack_wt<<<64, 256, 0, stream>>>(Wq, WQKVT);
    pack_wt<<<64, 256, 0, stream>>>(Wk, WQKVT + 128 * 128);
    pack_wt<<<64, 256, 0, stream>>>(Wv, WQKVT + 256 * 128);
    pack_wt<<<64, 256, 0, stream>>>(We2, WE23T);
    pack_wt<<<64, 256, 0, stream>>>(We3, WE23T + 128 * 128);
    bias_pack<<<3, 256, 0, stream>>>(bq, bk, bv, be2, be3, BQKV, BE23);

    // CSR build (independent of GEMMs)
    csr_hist<<<2000, 256, 0, stream>>>(eidx, dcnt);
    scan50k<<<1, 1024, 0, stream>>>(dcnt, rowptr, cursor);
    csr_scatter<<<2000, 256, 0, stream>>>(eidx, cursor, elist);

    gemm_node<<<391, 256, 0, stream>>>(x, WQKVT, BQKV, qkv, NN, 384);
    gemm_node<<<4000, 256, 0, stream>>>(eatt, WE23T, BE23, Cc, NE, 256);

    pass1<<<128000, 256, 0, stream>>>(eidx, qkv, Cc, ex1, ex2);
    pass2_gather<<<12500, 256, 0, stream>>>(eidx, rowptr, elist, qkv, Cc, ex1, ex2, agg);

    gemm_d128_o32<<<6250, 256, 0, stream>>>(agg, Wcon, xgat);
    bn_stats<<<256, 256, 0, stream>>>(xgat, stats);
    bn_gelu<<<6250, 256, 0, stream>>>(xgat, stats, bnw, bnb, out0);

    gemm_d128_o32<<<32000, 256, 0, stream>>>(eatt, Wh1, xh);
    gemm_d128_o32<<<6250, 256, 0, stream>>>(x, Wh2, attr);
    hyper_scatter<<<32000, 256, 0, stream>>>(xh, eidx, o1acc, degb);
    o1_finalize<<<6250, 256, 0, stream>>>(o1acc, degb, attr, o1);
    edge_out<<<32000, 256, 0, stream>>>(o1, eidx, bh, out1);
}

// Round 4
// 1339.079 us; speedup vs baseline: 1.0889x; 1.0889x over previous
//
#include <hip/hip_runtime.h>
#include <math.h>

#define NN 50000
#define NE 512000
#define NE2 256000
#define SCALE 0.17677669529663687f   // 1/sqrt(32)
#define EPSV 1e-5f

// ---- workspace layout (float offsets), total ~404 MB of ~1 GiB ----
#define OFF_QKV     0UL           // 50000*384 bf16
#define OFF_CC      9600000UL     // 512000*256 bf16  [ea2 | ea3]
#define OFF_EX1     75136000UL    // 512000*4 f32
#define OFF_EX2     77184000UL
#define OFF_AGG     79232000UL    // 50000*128 f32
#define OFF_XH      85632000UL    // 256000*32 f32
#define OFF_ATTR    93824000UL    // 50000*32
#define OFF_O1      95424000UL
#define OFF_XGAT    97024000UL
#define OFF_WQKVT   98624000UL    // 384*128 bf16
#define OFF_WE23T   98648576UL    // 256*128 bf16
#define OFF_BQKV    98664960UL    // 384 f32
#define OFF_BE23    98665344UL    // 256 f32
#define OFF_ROWPTR  98665600UL    // 50001 int
#define OFF_CURSOR  98715604UL    // 50000 int
#define OFF_ELIST   98765604UL    // 512000 int
// ---- zero region ----
#define OFF_DCNT    99277604UL    // 50000 int
#define OFF_O1ACC   99327604UL    // 50000*32 f32
#define OFF_DEGB    100927604UL   // 50000 f32
#define OFF_STATS   100977604UL   // 64 f32
#define ZERO_START  OFF_DCNT
#define ZERO_END    100977668UL

typedef __attribute__((ext_vector_type(8))) short bf16x8;
typedef __attribute__((ext_vector_type(8))) unsigned short us8;
typedef __attribute__((ext_vector_type(4))) float f32x4;

__device__ __forceinline__ unsigned short f2bf(float f) {
    unsigned int u = __float_as_uint(f);
    return (unsigned short)((u + 0x8000u) >> 16);   // round-half-up (1-ulp ties vs RNE)
}
__device__ __forceinline__ float bf2f(unsigned short u) {
    return __uint_as_float(((unsigned int)u) << 16);
}
// pack bf16(x) into low16, bf16(y) into high16, 3 VALU ops
__device__ __forceinline__ unsigned int pkbf(float x, float y) {
    unsigned int ux = __float_as_uint(x) + 0x8000u;
    unsigned int uy = __float_as_uint(y) + 0x8000u;
    return __builtin_amdgcn_perm(uy, ux, 0x07060302);
}

// ---------------- pack all weights (transposed bf16) + biases, one launch ----------------
__global__ void pack_all(const float* __restrict__ Wq, const float* __restrict__ Wk,
                         const float* __restrict__ Wv, const float* __restrict__ We2,
                         const float* __restrict__ We3,
                         const float* __restrict__ bq, const float* __restrict__ bk,
                         const float* __restrict__ bv, const float* __restrict__ be2,
                         const float* __restrict__ be3,
                         unsigned short* __restrict__ WQKVT, unsigned short* __restrict__ WE23T,
                         float* __restrict__ BQKV, float* __restrict__ BE23) {
    const int idx = blockIdx.x * 256 + threadIdx.x;   // 5*16384 + 640
    if (idx < 5 * 16384) {
        const int w = idx >> 14;
        const int r = idx & 16383;
        const int j = r >> 7;
        const int k = r & 127;
        const float* W = (w == 0) ? Wq : (w == 1) ? Wk : (w == 2) ? Wv : (w == 3) ? We2 : We3;
        const float val = W[k * 128 + j];
        if (w < 3) WQKVT[w * 16384 + r] = f2bf(val);
        else       WE23T[(w - 3) * 16384 + r] = f2bf(val);
    } else if (idx < 5 * 16384 + 640) {
        const int j = idx - 5 * 16384;
        if (j < 384) BQKV[j] = (j < 128) ? bq[j] : (j < 256 ? bk[j - 128] : bv[j - 256]);
        else {
            const int p = j - 384;
            BE23[p] = (p < 128) ? be2[p] : be3[p - 128];
        }
    }
}

// ---------------- MFMA GEMM: out = bf16(A(Mx128 f32) @ Bt^T + bias) ----------------
// Bt is (Ntot x 128) bf16 (row j = output column j). Tile 128M x 128N, slab loop over N.
// Epilogue: C-tile staged through LDS (aliases Bs) -> dwordx4 coalesced stores.
__global__ __launch_bounds__(256)
void gemm_node(const float* __restrict__ A, const unsigned short* __restrict__ Bt,
               const float* __restrict__ bias, unsigned short* __restrict__ out,
               int M, int Ntot) {
    __shared__ unsigned short As[2][128 * 72];
    __shared__ unsigned short Bs[2][128 * 72];    // epilogue: aliased as Cs[128][136]
    unsigned short* Cs = &Bs[0][0];
    const int tid = threadIdx.x;
    const int wave = tid >> 6;
    const int lane = tid & 63;
    const int quad = lane >> 4;
    const int l16 = lane & 15;
    const int m0 = (wave & 1) * 64;
    const int n0 = (wave >> 1) * 64;
    const size_t r0 = (size_t)blockIdx.x * 128;

    // stage A (both K-halves), fp32 -> bf16 packed
    #pragma unroll
    for (int kh = 0; kh < 2; kh++) {
        #pragma unroll
        for (int i = 0; i < 8; i++) {
            const int q = tid + 256 * i;
            const int row = q >> 4;
            const int c4 = q & 15;
            const long gr = (long)r0 + row;
            float4 a4 = {0.f, 0.f, 0.f, 0.f};
            if (gr < M) a4 = *(const float4*)(A + gr * 128 + kh * 64 + c4 * 4);
            uint2 p;
            p.x = pkbf(a4.x, a4.y);
            p.y = pkbf(a4.z, a4.w);
            *(uint2*)(&As[kh][row * 72 + c4 * 4]) = p;
        }
    }
    const int nslab = Ntot >> 7;
    for (int s = 0; s < nslab; s++) {
        __syncthreads();   // A visible (s=0); prev-slab Cs reads done (s>0)
        // stage Bs
        {
            const int n = tid >> 1;
            const int koff = (tid & 1) * 32;
            #pragma unroll
            for (int kh = 0; kh < 2; kh++) {
                const unsigned short* src = Bt + (size_t)(s * 128 + n) * 128 + kh * 64 + koff;
                #pragma unroll
                for (int u = 0; u < 4; u++)
                    *(us8*)(&Bs[kh][n * 72 + koff + 8 * u]) = *(const us8*)(src + 8 * u);
            }
        }
        __syncthreads();
        f32x4 acc[4][4];
        #pragma unroll
        for (int i = 0; i < 4; i++)
            #pragma unroll
            for (int j = 0; j < 4; j++) acc[i][j] = (f32x4){0.f, 0.f, 0.f, 0.f};
        #pragma unroll
        for (int kh = 0; kh < 2; kh++) {
            #pragma unroll
            for (int kc = 0; kc < 64; kc += 32) {
                bf16x8 af[4], bfr[4];
                #pragma unroll
                for (int i = 0; i < 4; i++)
                    af[i] = *(const bf16x8*)(&As[kh][(m0 + 16 * i + l16) * 72 + kc + quad * 8]);
                #pragma unroll
                for (int j = 0; j < 4; j++)
                    bfr[j] = *(const bf16x8*)(&Bs[kh][(n0 + 16 * j + l16) * 72 + kc + quad * 8]);
                #pragma unroll
                for (int i = 0; i < 4; i++)
                    #pragma unroll
                    for (int j = 0; j < 4; j++)
                        acc[i][j] = __builtin_amdgcn_mfma_f32_16x16x32_bf16(af[i], bfr[j], acc[i][j], 0, 0, 0);
            }
        }
        __syncthreads();   // all MFMA reads of Bs done before Cs overwrite
        // write C tile (bf16, +bias) into LDS
        #pragma unroll
        for (int j = 0; j < 4; j++) {
            const int col = n0 + 16 * j + l16;
            const float bcol = bias[s * 128 + col];
            #pragma unroll
            for (int i = 0; i < 4; i++) {
                const int rowb = m0 + 16 * i + quad * 4;
                #pragma unroll
                for (int r = 0; r < 4; r++)
                    Cs[(rowb + r) * 136 + col] = f2bf(acc[i][j][r] + bcol);
            }
        }
        __syncthreads();
        // coalesced store: 2 threads per row, 128B each (8 x dwordx4)
        {
            const int row = tid >> 1;
            const int half = tid & 1;
            const long gr = (long)r0 + row;
            if (gr < M) {
                unsigned short* dst = out + gr * Ntot + s * 128 + half * 64;
                const unsigned short* srcl = &Cs[row * 136 + half * 64];
                #pragma unroll
                for (int u = 0; u < 8; u++)
                    *(us8*)(dst + 8 * u) = *(const us8*)(srcl + 8 * u);
            }
        }
    }
}

// ---------------- pass1: per-edge exp-logits (no atomics) ----------------
__global__ void pass1(const int* __restrict__ eidx, const unsigned short* __restrict__ qkv,
                      const unsigned short* __restrict__ Cc,
                      float* __restrict__ ex1, float* __restrict__ ex2) {
    const size_t e = (size_t)blockIdx.x * 4 + (threadIdx.x >> 6);
    const int lane = threadIdx.x & 63;
    const int src = eidx[e];
    const int dst = eidx[NE + e];
    const unsigned int qp = *(const unsigned int*)(qkv + (size_t)dst * 384 + 2 * lane);
    const unsigned int kp = *(const unsigned int*)(qkv + (size_t)src * 384 + 128 + 2 * lane);
    const unsigned int ep = *(const unsigned int*)(Cc + (size_t)e * 256 + 2 * lane);
    const float qx = bf2f((unsigned short)(qp & 0xFFFF)), qy = bf2f((unsigned short)(qp >> 16));
    const float kx = bf2f((unsigned short)(kp & 0xFFFF)), ky = bf2f((unsigned short)(kp >> 16));
    const float e2x = bf2f((unsigned short)(ep & 0xFFFF)), e2y = bf2f((unsigned short)(ep >> 16));
    float p1 = qx * kx + qy * ky;
    float p2 = qx * e2x + qy * e2y;
    #pragma unroll
    for (int off = 8; off > 0; off >>= 1) {
        p1 += __shfl_down(p1, off, 16);
        p2 += __shfl_down(p2, off, 16);
    }
    if ((lane & 15) == 0) {
        const int h = lane >> 4;
        ex1[e * 4 + h] = __expf(p1 * SCALE);
        ex2[e * 4 + h] = __expf(p2 * SCALE);
    }
}

// ---------------- CSR build ----------------
__global__ void csr_hist(const int* __restrict__ eidx, int* __restrict__ dcnt) {
    const int e = blockIdx.x * 256 + threadIdx.x;
    atomicAdd(&dcnt[eidx[NE + e]], 1);
}

__global__ __launch_bounds__(1024)
void scan50k(const int* __restrict__ dcnt, int* __restrict__ rowptr, int* __restrict__ cursor) {
    __shared__ int part[1024];
    const int t = threadIdx.x;
    const int per = 49;
    const int base = t * per;
    int s = 0;
    for (int i = 0; i < per; i++) {
        const int n = base + i;
        if (n < NN) s += dcnt[n];
    }
    part[t] = s;
    __syncthreads();
    for (int off = 1; off < 1024; off <<= 1) {
        const int vv = (t >= off) ? part[t - off] : 0;
        __syncthreads();
        part[t] += vv;
        __syncthreads();
    }
    int run = (t == 0) ? 0 : part[t - 1];
    for (int i = 0; i < per; i++) {
        const int n = base + i;
        if (n < NN) {
            rowptr[n] = run;
            cursor[n] = run;
            run += dcnt[n];
        }
    }
    if (base <= NN - 1 && NN - 1 < base + per) rowptr[NN] = run;
}

__global__ void csr_scatter(const int* __restrict__ eidx, int* __restrict__ cursor,
                            int* __restrict__ elist) {
    const int e = blockIdx.x * 256 + threadIdx.x;
    const int dst = eidx[NE + e];
    const int pos = atomicAdd(&cursor[dst], 1);
    elist[pos] = e;
}

// ---------------- pass2: per-node gather (no atomics) ----------------
__global__ void pass2_gather(const int* __restrict__ eidx, const int* __restrict__ rowptr,
                             const int* __restrict__ elist,
                             const unsigned short* __restrict__ qkv,
                             const unsigned short* __restrict__ Cc,
                             const float* __restrict__ ex1, const float* __restrict__ ex2,
                             float* __restrict__ agg) {
    const int n = blockIdx.x * 4 + (threadIdx.x >> 6);
    const int lane = threadIdx.x & 63;
    const int h = lane >> 4;
    const int beg = rowptr[n], end = rowptr[n + 1];
    float s1 = 0.f, s2 = 0.f;
    for (int i = beg; i < end; i++) {
        const int e = elist[i];
        s1 += ex1[(size_t)e * 4 + h];
        s2 += ex2[(size_t)e * 4 + h];
    }
    const float r1 = 1.f / (s1 + 1e-16f);
    const float r2 = 1.f / (s2 + 1e-16f);
    float ax = 0.f, ay = 0.f;
    for (int i = beg; i < end; i++) {
        const int e = elist[i];
        const int src = eidx[e];
        const float w1 = ex1[(size_t)e * 4 + h] * r1;
        const float w2 = ex2[(size_t)e * 4 + h] * r2;
        const unsigned int vp = *(const unsigned int*)(qkv + (size_t)src * 384 + 256 + 2 * lane);
        const unsigned int e3 = *(const unsigned int*)(Cc + (size_t)e * 256 + 128 + 2 * lane);
        ax += w1 * bf2f((unsigned short)(vp & 0xFFFF)) + w2 * bf2f((unsigned short)(e3 & 0xFFFF));
        ay += w1 * bf2f((unsigned short)(vp >> 16)) + w2 * bf2f((unsigned short)(e3 >> 16));
    }
    *(float2*)(agg + (size_t)n * 128 + 2 * lane) = make_float2(ax, ay);
}

// ---------------- generic (M x 128) @ (128 x 32) fp32 ----------------
__global__ void gemm_d128_o32(const float* __restrict__ A, const float* __restrict__ W,
                              float* __restrict__ out) {
    __shared__ float as[8 * 128];
    const int tid = threadIdx.x;
    const int p = tid & 31;
    const int mm = tid >> 5;
    const size_t m0 = (size_t)blockIdx.x * 8;
    ((float4*)as)[tid] = ((const float4*)(A + m0 * 128))[tid];
    __syncthreads();
    float c0 = 0.f, c1 = 0.f, c2 = 0.f, c3 = 0.f;
    const float4* as4 = (const float4*)as;
    #pragma unroll 8
    for (int i = 0; i < 32; i++) {
        const float4 a4 = as4[mm*32 + i];
        c0 += a4.x * W[(4*i+0)*32 + p];
        c1 += a4.y * W[(4*i+1)*32 + p];
        c2 += a4.z * W[(4*i+2)*32 + p];
        c3 += a4.w * W[(4*i+3)*32 + p];
    }
    out[(m0 + mm)*32 + p] = (c0 + c1) + (c2 + c3);
}

// ---------------- BN stats ----------------
__global__ void bn_stats(const float* __restrict__ xg, float* __restrict__ stats) {
    __shared__ float ls[256], lss[256];
    const int tid = threadIdx.x;
    float s = 0.f, ss = 0.f;
    for (size_t i = (size_t)blockIdx.x*256 + tid; i < (size_t)NN*32; i += (size_t)gridDim.x*256) {
        const float val = xg[i];
        s += val; ss += val * val;
    }
    ls[tid] = s; lss[tid] = ss;
    __syncthreads();
    if (tid < 32) {
        float as_ = 0.f, ass = 0.f;
        #pragma unroll
        for (int w = 0; w < 8; w++) { as_ += ls[tid + 32*w]; ass += lss[tid + 32*w]; }
        atomicAdd(&stats[tid], as_);
        atomicAdd(&stats[32 + tid], ass);
    }
}

// ---------------- BN apply + exact GELU ----------------
__global__ void bn_gelu(const float* __restrict__ xg, const float* __restrict__ stats,
                        const float* __restrict__ bnw, const float* __restrict__ bnb,
                        float* __restrict__ out) {
    const size_t i = (size_t)blockIdx.x * 256 + threadIdx.x;
    const int c = i & 31;
    const float mu = stats[c] * (1.0f / NN);
    const float var = stats[32 + c] * (1.0f / NN) - mu * mu;
    const float xn = bnw[c] * (xg[i] - mu) * rsqrtf(var + EPSV) + bnb[c];
    out[i] = 0.5f * xn * (1.0f + erff(xn * 0.70710678118654752f));
}

// ---------------- hypergraph scatter ----------------
__global__ void hyper_scatter(const float* __restrict__ xh, const int* __restrict__ eidx,
                              float* __restrict__ o1acc, float* __restrict__ degb) {
    const int tid = threadIdx.x;
    const int c = tid & 31;
    const size_t i = (size_t)blockIdx.x * 8 + (tid >> 5);
    const int src = eidx[i];
    const int dst = eidx[NE + i];
    const float xv = xh[i*32 + c];
    atomicAdd(&o1acc[(size_t)src*32 + c], xv);
    atomicAdd(&o1acc[(size_t)dst*32 + c], xv);
    if (c == 0) {
        atomicAdd(&degb[src], 1.0f);
        atomicAdd(&degb[dst], 1.0f);
    }
}

__global__ void o1_finalize(const float* __restrict__ o1acc, const float* __restrict__ degb,
                            const float* __restrict__ attr, float* __restrict__ o1) {
    const size_t i = (size_t)blockIdx.x * 256 + threadIdx.x;
    const int n = (int)(i >> 5);
    const float d = degb[n];
    const float binv = d > 0.f ? 1.0f / d : 0.0f;
    o1[i] = o1acc[i] * binv + attr[i];
}

__global__ void edge_out(const float* __restrict__ o1, const int* __restrict__ eidx,
                         const float* __restrict__ bh, float* __restrict__ out2) {
    const size_t idx = (size_t)blockIdx.x * 256 + threadIdx.x;
    const size_t i = idx >> 5;
    const int c = (int)(idx & 31);
    const int src = eidx[i];
    const int dst = eidx[NE + i];
    out2[idx] = 0.5f * (o1[(size_t)src*32 + c] + o1[(size_t)dst*32 + c]) + bh[c];
}

extern "C" void kernel_launch(void* const* d_in, const int* in_sizes, int n_in,
                              void* d_out, int out_size, void* d_ws, size_t ws_size,
                              hipStream_t stream) {
    const float* x    = (const float*)d_in[0];
    const float* eatt = (const float*)d_in[1];
    const float* Wq   = (const float*)d_in[2];
    const float* bq   = (const float*)d_in[3];
    const float* Wk   = (const float*)d_in[4];
    const float* bk   = (const float*)d_in[5];
    const float* Wv   = (const float*)d_in[6];
    const float* bv   = (const float*)d_in[7];
    const float* We2  = (const float*)d_in[8];
    const float* be2  = (const float*)d_in[9];
    const float* We3  = (const float*)d_in[10];
    const float* be3  = (const float*)d_in[11];
    const float* Wcon = (const float*)d_in[12];
    const float* bnw  = (const float*)d_in[13];
    const float* bnb  = (const float*)d_in[14];
    const float* Wh1  = (const float*)d_in[15];
    const float* Wh2  = (const float*)d_in[16];
    const float* bh   = (const float*)d_in[17];
    const int*   eidx = (const int*)d_in[18];

    float* ws = (float*)d_ws;
    unsigned short* qkv   = (unsigned short*)(ws + OFF_QKV);
    unsigned short* Cc    = (unsigned short*)(ws + OFF_CC);
    float* ex1   = ws + OFF_EX1;
    float* ex2   = ws + OFF_EX2;
    float* agg   = ws + OFF_AGG;
    float* xh    = ws + OFF_XH;
    float* attr  = ws + OFF_ATTR;
    float* o1    = ws + OFF_O1;
    float* xgat  = ws + OFF_XGAT;
    unsigned short* WQKVT = (unsigned short*)(ws + OFF_WQKVT);
    unsigned short* WE23T = (unsigned short*)(ws + OFF_WE23T);
    float* BQKV  = ws + OFF_BQKV;
    float* BE23  = ws + OFF_BE23;
    int* rowptr  = (int*)(ws + OFF_ROWPTR);
    int* cursor  = (int*)(ws + OFF_CURSOR);
    int* elist   = (int*)(ws + OFF_ELIST);
    int* dcnt    = (int*)(ws + OFF_DCNT);
    float* o1acc = ws + OFF_O1ACC;
    float* degb  = ws + OFF_DEGB;
    float* stats = ws + OFF_STATS;
    float* out0  = (float*)d_out;
    float* out1  = (float*)d_out + (size_t)NN * 32;

    hipMemsetAsync(ws + ZERO_START, 0, (ZERO_END - ZERO_START) * sizeof(float), stream);

    pack_all<<<323, 256, 0, stream>>>(Wq, Wk, Wv, We2, We3, bq, bk, bv, be2, be3,
                                      WQKVT, WE23T, BQKV, BE23);

    // CSR build (independent of GEMMs)
    csr_hist<<<2000, 256, 0, stream>>>(eidx, dcnt);
    scan50k<<<1, 1024, 0, stream>>>(dcnt, rowptr, cursor);
    csr_scatter<<<2000, 256, 0, stream>>>(eidx, cursor, elist);

    gemm_node<<<391, 256, 0, stream>>>(x, WQKVT, BQKV, qkv, NN, 384);
    gemm_node<<<4000, 256, 0, stream>>>(eatt, WE23T, BE23, Cc, NE, 256);

    pass1<<<128000, 256, 0, stream>>>(eidx, qkv, Cc, ex1, ex2);
    pass2_gather<<<12500, 256, 0, stream>>>(eidx, rowptr, elist, qkv, Cc, ex1, ex2, agg);

    gemm_d128_o32<<<6250, 256, 0, stream>>>(agg, Wcon, xgat);
    bn_stats<<<256, 256, 0, stream>>>(xgat, stats);
    bn_gelu<<<6250, 256, 0, stream>>>(xgat, stats, bnw, bnb, out0);

    gemm_d128_o32<<<32000, 256, 0, stream>>>(eatt, Wh1, xh);
    gemm_d128_o32<<<6250, 256, 0, stream>>>(x, Wh2, attr);
    hyper_scatter<<<32000, 256, 0, stream>>>(xh, eidx, o1acc, degb);
    o1_finalize<<<6250, 256, 0, stream>>>(o1acc, degb, attr, o1);
    edge_out<<<32000, 256, 0, stream>>>(o1, eidx, bh, out1);
}